// Round 4
// baseline (83.727 us; speedup 1.0000x reference)
//
#include <hip/hip_runtime.h>
#include <hip/hip_bf16.h>

// Direct state-vector simulation of the 7-effective-wire circuit.
// Layout: batch element <-> 16 lanes (sub-lane L in [0,16)), 8 amplitudes per
// thread (reg index r in [0,8)). 7-bit state index s = L*8 + r, wire w maps to
// state bit (6-w):
//   wires 0..3 -> lane bits 3..0  (shfl_xor masks 8,4,2,1)
//   wires 4..6 -> reg  bits 2..0  (reg masks 4,2,1)
// All circuit loops fully unrolled so reg-reg CNOTs become register renaming.
//
// Dtype evidence log:
//   R1 (fp32 in / bf16 out): finite-but-wrong, absmax 0.3125
//   R2 (bf16 in):            NaN -> inputs ARE fp32
//   R3 (LDS impl, bf16 out): absmax 0.3125 == R1 exactly -> math identical
//     across two independent impls; the shared bug was the OUTPUT dtype.
//   Reference returns jnp.float32 -> d_out is float* (contract: "reference's
//   OUTPUT dtype ... else float*"). This round: fp32 stores.

#define DEVI __device__ __forceinline__

DEVI void ry_lane(float v[8], int lmask, float c, float s, int L) {
    float ss = (L & lmask) ? s : -s;   // bit=1: c*me + s*partner ; bit=0: c*me - s*partner
#pragma unroll
    for (int r = 0; r < 8; ++r) {
        float p = __shfl_xor(v[r], lmask, 64);
        v[r] = fmaf(c, v[r], ss * p);
    }
}

DEVI void ry_reg(float v[8], int rmask, float c, float s) {
#pragma unroll
    for (int r = 0; r < 8; ++r) {
        if (!(r & rmask)) {
            int r2 = r | rmask;
            float a = v[r], b = v[r2];
            v[r]  = fmaf(c, a, -(s * b));   // a' = c*a - s*b
            v[r2] = fmaf(c, b,  (s * a));   // b' = s*a + c*b
        }
    }
}

DEVI void cnot_ll(float v[8], int cmask, int tmask, int L) {
    bool hit = (L & cmask) != 0;
#pragma unroll
    for (int r = 0; r < 8; ++r) {
        float p = __shfl_xor(v[r], tmask, 64);
        v[r] = hit ? p : v[r];
    }
}

DEVI void cnot_lr(float v[8], int cmask, int trmask, int L) {
    bool hit = (L & cmask) != 0;
    float t[8];
#pragma unroll
    for (int r = 0; r < 8; ++r) t[r] = v[r];
#pragma unroll
    for (int r = 0; r < 8; ++r) v[r] = hit ? t[r ^ trmask] : t[r];
}

DEVI void cnot_rl(float v[8], int crmask, int tmask) {
#pragma unroll
    for (int r = 0; r < 8; ++r)
        if (r & crmask) v[r] = __shfl_xor(v[r], tmask, 64);
}

DEVI void cnot_rr(float v[8], int crmask, int trmask) {
#pragma unroll
    for (int r = 0; r < 8; ++r)
        if ((r & crmask) && !(r & trmask)) {
            float tmp = v[r]; v[r] = v[r | trmask]; v[r | trmask] = tmp;
        }
}

DEVI void RY(float v[8], int w, float c, float s, int L) {
    if (w < 4) ry_lane(v, 8 >> w, c, s, L);
    else       ry_reg(v, 1 << (6 - w), c, s);
}

DEVI void CNOT(float v[8], int cw, int tw, int L) {
    if (cw < 4 && tw < 4)       cnot_ll(v, 8 >> cw, 8 >> tw, L);
    else if (cw < 4)            cnot_lr(v, 8 >> cw, 1 << (6 - tw), L);
    else if (tw >= 4)           cnot_rr(v, 1 << (6 - cw), 1 << (6 - tw));
    else                        cnot_rl(v, 1 << (6 - cw), 8 >> tw);
}

__global__ __launch_bounds__(256) void qcnn_kernel(
    const float* __restrict__ x,
    const float* __restrict__ QC1, const float* __restrict__ QC2,
    const float* __restrict__ QC3, const float* __restrict__ QP1,
    const float* __restrict__ QP2, const float* __restrict__ QP3,
    const float* __restrict__ QF,
    float* __restrict__ out, int B)
{
    const int tid  = threadIdx.x;
    const int lane = tid & 63;
    const int wave = tid >> 6;
    const int L    = lane & 15;        // sub-lane within batch group
    const int g    = lane >> 4;        // batch group within wave
    const int b    = blockIdx.x * 16 + wave * 4 + g;
    if (b >= B) return;                // B=4096 -> never taken

    // ---- load unnormalized amplitudes: v[r] = x[b][L*8 + r] ----
    float v[8];
    const float* xb = x + (size_t)b * 128 + L * 8;
    float4 lo = *reinterpret_cast<const float4*>(xb);
    float4 hi = *reinterpret_cast<const float4*>(xb + 4);
    v[0]=lo.x; v[1]=lo.y; v[2]=lo.z; v[3]=lo.w;
    v[4]=hi.x; v[5]=hi.y; v[6]=hi.z; v[7]=hi.w;

    float cc[12], ss[12];

    // ---- conv block 1 ----
#pragma unroll
    for (int k = 0; k < 12; ++k) __sincosf(0.5f * QC1[k], &ss[k], &cc[k]);
#pragma unroll
    for (int i = 0; i < 7; ++i) {
        const int i2 = (i + 1) % 7;
#pragma unroll
        for (int q = 0; q < 6; ++q) {
            RY(v, i,  cc[2*q],   ss[2*q],   L);
            RY(v, i2, cc[2*q+1], ss[2*q+1], L);
            CNOT(v, i, i2, L);
        }
    }

    // ---- pool 1 ----
    {
        float c0, s0, c1, s1;
        __sincosf(0.5f * QP1[0], &s0, &c0);
        __sincosf(0.5f * QP1[1], &s1, &c1);
#pragma unroll
        for (int i = 0; i < 3; ++i) {
            RY(v, i,     c0,  s0, L);
            RY(v, i + 3, c1,  s1, L);
            CNOT(v, i, i + 3, L);
            RY(v, i + 3, c1, -s1, L);
        }
    }

    // ---- conv block 2 (i==6: RY partner wire 3, CNOT target wire 0) ----
#pragma unroll
    for (int k = 0; k < 12; ++k) __sincosf(0.5f * QC2[k], &ss[k], &cc[k]);
#pragma unroll
    for (int i = 3; i < 7; ++i) {
        const int ti = (i != 6) ? (i + 1) : 3;  // RY partner wire
        const int ct = (i != 6) ? (i + 1) : 0;  // CNOT target wire
#pragma unroll
        for (int q = 0; q < 6; ++q) {
            RY(v, i,  cc[2*q],   ss[2*q],   L);
            RY(v, ti, cc[2*q+1], ss[2*q+1], L);
            CNOT(v, i, ct, L);
        }
    }

    // ---- pool 2 ----
    {
        float c0, s0, c1, s1;
        __sincosf(0.5f * QP2[0], &s0, &c0);
        __sincosf(0.5f * QP2[1], &s1, &c1);
#pragma unroll
        for (int i = 3; i < 5; ++i) {
            RY(v, i,     c0,  s0, L);
            RY(v, i + 2, c1,  s1, L);
            CNOT(v, i, i + 2, L);
            RY(v, i + 2, c1, -s1, L);
        }
    }

    // ---- conv block 3 (leaked loop var -> CNOT(4,5)) ----
#pragma unroll
    for (int k = 0; k < 12; ++k) __sincosf(0.5f * QC3[k], &ss[k], &cc[k]);
#pragma unroll
    for (int q = 0; q < 6; ++q) {
        RY(v, 5, cc[2*q],   ss[2*q],   L);
        RY(v, 6, cc[2*q+1], ss[2*q+1], L);
        CNOT(v, 4, 5, L);
    }

    // ---- pool 3 (leaked loop var -> CNOT(4,6)) ----
    {
        float c0, s0, c1, s1;
        __sincosf(0.5f * QP3[0], &s0, &c0);
        __sincosf(0.5f * QP3[1], &s1, &c1);
        RY(v, 5, c0,  s0, L);
        RY(v, 6, c1,  s1, L);
        CNOT(v, 4, 6, L);
        RY(v, 6, c1, -s1, L);
    }

    // ---- final block: RY(a)RY(b)RY(c)RY(d) on wire 5 == RY(a+b+c+d) ----
    {
        float cf, sf;
        __sincosf(0.5f * (QF[0] + QF[1] + QF[2] + QF[3]), &sf, &cf);
        RY(v, 5, cf, sf, L);
    }
    CNOT(v, 5, 6, L);
    CNOT(v, 6, 5, L);
    // CNOT(7,5), CNOT(8,6): controls fixed in |0> -> identity, omitted.

    // ---- epilogue: probs over wires (5,6) = (s&3), normalize, softmax ----
    float gs[4];
#pragma unroll
    for (int j = 0; j < 4; ++j) gs[j] = v[j]*v[j] + v[j+4]*v[j+4];
#pragma unroll
    for (int m = 1; m < 16; m <<= 1) {
#pragma unroll
        for (int j = 0; j < 4; ++j) gs[j] += __shfl_xor(gs[j], m, 64);
    }
    // circuit is orthogonal -> gs sums to ||x||^2; dividing implements
    // AmplitudeEmbedding(normalize=True)
    float n  = gs[0] + gs[1] + gs[2] + gs[3];
    float p0 = gs[0] / n, p1 = gs[1] / n, p2 = gs[2] / n, p3 = gs[3] / n;
    float mx = fmaxf(fmaxf(p0, p1), fmaxf(p2, p3));
    float e0 = __expf(p0 - mx), e1 = __expf(p1 - mx);
    float e2 = __expf(p2 - mx), e3 = __expf(p3 - mx);
    float es = e0 + e1 + e2 + e3;
    float inv = 1.0f / es;

    if (L == 0) {
        float4 o = make_float4(e0 * inv, e1 * inv, e2 * inv, e3 * inv);
        *reinterpret_cast<float4*>(out + (size_t)b * 4) = o;   // fp32 OUTPUT
    }
}

extern "C" void kernel_launch(void* const* d_in, const int* in_sizes, int n_in,
                              void* d_out, int out_size, void* d_ws, size_t ws_size,
                              hipStream_t stream) {
    const float* x   = (const float*)d_in[0];
    const float* QC1 = (const float*)d_in[1];
    const float* QC2 = (const float*)d_in[2];
    const float* QC3 = (const float*)d_in[3];
    const float* QP1 = (const float*)d_in[4];
    const float* QP2 = (const float*)d_in[5];
    const float* QP3 = (const float*)d_in[6];
    const float* QF  = (const float*)d_in[7];
    float* out = (float*)d_out;

    const int B = in_sizes[0] / 128;      // 4096
    const int blocks = (B + 15) / 16;     // 16 batch elements per 256-thread block
    qcnn_kernel<<<blocks, 256, 0, stream>>>(x, QC1, QC2, QC3, QP1, QP2, QP3, QF, out, B);
}